// Round 8
// baseline (166.200 us; speedup 1.0000x reference)
//
#include <hip/hip_runtime.h>
#include <hip/hip_bf16.h>
#include <math.h>

#define B 32
#define KLEN 2000
#define KDIM 512
#define QDIM 512
#define ADIM 512
#define VDIM 512
#define CONV_CH 10
#define CONV_K 201
#define NROWS (B*KLEN)

#define NKS  33                  // 528 / 16 (512 key + 10 conv + 1 bias + 5 pad)
#define ZERO16 {0,0,0,0,0,0,0,0,0,0,0,0,0,0,0,0}

typedef __attribute__((ext_vector_type(8)))  short bf16x8;
typedef __attribute__((ext_vector_type(16))) float f32x16;
typedef __attribute__((ext_vector_type(4)))  float f32x4;
typedef __attribute__((ext_vector_type(2)))  float f32x2;

__device__ __forceinline__ ushort f32_to_bf16(float f) {
    union { float f; unsigned int u; } v; v.f = f;
    unsigned int x = v.u;
    unsigned int r = (x + 0x7FFFu + ((x >> 16) & 1u)) >> 16;
    return (ushort)r;
}

__device__ __forceinline__ float fast_tanh(float x) {
    // tanh(x) = 1 - 2/(e^(2x)+1); stable at both extremes
    return 1.0f - 2.0f / (__expf(2.0f * x) + 1.0f);
}

#define MFMA32(a, bfr, c) __builtin_amdgcn_mfma_f32_32x32x16_bf16(a, bfr, c, 0, 0, 0)

// ---- K0: pack W_ext = [Wk | Wconv | bk | 0pad] into MFMA-B lane layout ----
// layout: [nt(16)][ks(33)][lane(64)][8 bf16]; lane = h*32+r;
// holds B[k = ks*16 + h*8 + jj][col = nt*32 + r]
__global__ void k_pack_w(const float* __restrict__ Wk, const float* __restrict__ Wconv,
                         const float* __restrict__ bk, ushort* __restrict__ wp) {
    int t = blockIdx.x * 256 + threadIdx.x;        // 33792 16B-chunks
    int lane = t & 63;
    int idx = t >> 6;
    int ks = idx % NKS, nt = idx / NKS;
    int h = lane >> 5, r = lane & 31;
    int a = nt * 32 + r;
    int j0 = ks * 16 + h * 8;
    union { uint4 v; ushort u[8]; } pk;
    #pragma unroll
    for (int jj = 0; jj < 8; jj++) {
        int j = j0 + jj;
        float val;
        if (j < 512)       val = Wk[a * KDIM + j];
        else if (j < 522)  val = Wconv[a * CONV_CH + (j - 512)];
        else if (j == 522) val = bk[a];
        else               val = 0.f;
        pk.u[jj] = f32_to_bf16(val);
    }
    *(uint4*)(wp + (size_t)t * 8) = pk.v;
}

// ---- K1: qproj[b][a] = dot(query[b], Wq[a]) -----------------------------
__global__ void k_qproj(const float* __restrict__ query, const float* __restrict__ Wq,
                        float* __restrict__ qproj) {
    int t = blockIdx.x * 256 + threadIdx.x;        // 16384
    int b = t >> 9, a = t & 511;
    const f32x4* q = (const f32x4*)(query + b * QDIM);
    const f32x4* w = (const f32x4*)(Wq + a * QDIM);
    float acc = 0.f;
    #pragma unroll 4
    for (int i = 0; i < 128; i++) {
        f32x4 qv = q[i], wv = w[i];
        acc += qv[0]*wv[0] + qv[1]*wv[1] + qv[2]*wv[2] + qv[3]*wv[3];
    }
    qproj[t] = acc;
}

// ---- K2: conv_feat[b][c][k] = SAME cross-correlation --------------------
__global__ void k_conv(const float* __restrict__ aw_prev, const float* __restrict__ conv_w,
                       float* __restrict__ cf) {
    int t = blockIdx.x * 256 + threadIdx.x;
    if (t >= B * CONV_CH * KLEN) return;
    int k = t % KLEN;
    int c = (t / KLEN) % CONV_CH;
    int b = t / (KLEN * CONV_CH);
    const float* aw = aw_prev + b * KLEN;
    const float* w  = conv_w + c * CONV_K;
    int lo = k - 100;
    int t0 = lo < 0 ? -lo : 0;
    int t1 = (lo + CONV_K > KLEN) ? (KLEN - lo) : CONV_K;
    float acc = 0.f;
    for (int tt = t0; tt < t1; tt++) acc += w[tt] * aw[lo + tt];
    cf[t] = acc;
}

// ---- K3: fused kproj-ext GEMM + additive score --------------------------
// Block: 512 thr = 8 waves; each wave = 64 rows x 64 cols (2m x 2n MFMA block).
// A (key bf16, swizzled) in 64KB LDS staged once; B read from L2; no loop barriers.
// 2 blocks/CU -> 16 waves/CU. Writes per-colgroup partials ep[wc][row].
__global__ __launch_bounds__(512, 4)
void k_main(const float* __restrict__ key, const ushort* __restrict__ wp,
            const float* __restrict__ qproj, const float* __restrict__ cf,
            const float* __restrict__ vvec, float* __restrict__ ep) {
    __shared__ char Alds[65536];                   // 64 rows x 512 bf16, swizzled
    const int tid = threadIdx.x;
    const int wc = tid >> 6, lane = tid & 63;      // wc = col-group 0..7
    const int r = lane & 31, h = lane >> 5;
    const int row0 = blockIdx.x * 64;

    // ---- A_cf fragments: conv features + bias-one (rows r, 32+r) -------
    auto build_cf = [&](int row) -> bf16x8 {
        int b = row / KLEN, kpos = row % KLEN;
        const float* cfb = cf + ((size_t)b * CONV_CH) * KLEN + kpos;
        union { bf16x8 v8; ushort u[8]; } pk;
        if (h == 0) {
            #pragma unroll
            for (int jj = 0; jj < 8; jj++) pk.u[jj] = f32_to_bf16(cfb[(size_t)jj * KLEN]);
        } else {
            pk.u[0] = f32_to_bf16(cfb[(size_t)8 * KLEN]);
            pk.u[1] = f32_to_bf16(cfb[(size_t)9 * KLEN]);
            pk.u[2] = 0x3F80;  // 1.0f bf16 (bias column)
            pk.u[3] = 0; pk.u[4] = 0; pk.u[5] = 0; pk.u[6] = 0; pk.u[7] = 0;
        }
        return pk.v8;
    };
    bf16x8 Acf0 = build_cf(row0 + r);
    bf16x8 Acf1 = build_cf(row0 + 32 + r);

    // ---- stage key f32 -> bf16 into swizzled LDS ------------------------
    // chunk ch: row=ch>>6, cx=ch&63 covers bytes [cx*16,+16) of row.
    // swizzle: byte_off ^= (row&31)<<4 (read side uses same XOR -> <=2-way)
    #pragma unroll
    for (int i = 0; i < 8; i++) {
        int ch = tid + i * 512;
        int arow = ch >> 6, cx = ch & 63;
        const float* kp = key + (size_t)(row0 + arow) * KDIM + cx * 8;
        f32x4 f0 = __builtin_nontemporal_load((const f32x4*)kp);
        f32x4 f1 = __builtin_nontemporal_load((const f32x4*)(kp + 4));
        union { uint4 v; ushort u[8]; } pk;
        pk.u[0] = f32_to_bf16(f0[0]); pk.u[1] = f32_to_bf16(f0[1]);
        pk.u[2] = f32_to_bf16(f0[2]); pk.u[3] = f32_to_bf16(f0[3]);
        pk.u[4] = f32_to_bf16(f1[0]); pk.u[5] = f32_to_bf16(f1[1]);
        pk.u[6] = f32_to_bf16(f1[2]); pk.u[7] = f32_to_bf16(f1[3]);
        int off = arow * 1024 + cx * 16;
        off ^= (arow & 31) << 4;
        *(uint4*)(Alds + off) = pk.v;
    }
    __syncthreads();   // the only barrier

    // ---- main loop: K=512 from LDS, B fragments from L2 -----------------
    const ushort* bp0 = wp + ((size_t)(wc * 2 + 0) * NKS * 64 + lane) * 8;
    const ushort* bp1 = wp + ((size_t)(wc * 2 + 1) * NKS * 64 + lane) * 8;
    const int abase0 = r * 1024 + h * 16;
    const int abase1 = abase0 + 32768;
    const int swz = r << 4;

    f32x16 c00 = ZERO16, c01 = ZERO16;
    f32x16 c10 = ZERO16, c11 = ZERO16;

    #pragma unroll 4
    for (int ks = 0; ks < 32; ks++) {
        bf16x8 a0 = *(const bf16x8*)(Alds + ((abase0 + ks * 32) ^ swz));
        bf16x8 a1 = *(const bf16x8*)(Alds + ((abase1 + ks * 32) ^ swz));
        bf16x8 b0 = *(const bf16x8*)(bp0 + ks * 512);
        bf16x8 b1 = *(const bf16x8*)(bp1 + ks * 512);
        c00 = MFMA32(a0, b0, c00); c01 = MFMA32(a0, b1, c01);
        c10 = MFMA32(a1, b0, c10); c11 = MFMA32(a1, b1, c11);
    }
    {   // ks = 32: conv features + bias via register A fragments
        bf16x8 b0 = *(const bf16x8*)(bp0 + 32 * 512);
        bf16x8 b1 = *(const bf16x8*)(bp1 + 32 * 512);
        c00 = MFMA32(Acf0, b0, c00); c01 = MFMA32(Acf0, b1, c01);
        c10 = MFMA32(Acf1, b0, c10); c11 = MFMA32(Acf1, b1, c11);
    }

    // ---- epilogue: + qproj, tanh, * v, per-lane partial sums ------------
    const int colb = wc * 64 + r;                  // n0 col; n1 = colb+32
    const float v0 = vvec[colb], v1 = vvec[colb + 32];
    const int blo = row0 / KLEN;
    const int bhi = (row0 + 63) / KLEN;
    const int split = (blo + 1) * KLEN;
    const float ql0 = qproj[blo * ADIM + colb],      qh0 = qproj[bhi * ADIM + colb];
    const float ql1 = qproj[blo * ADIM + colb + 32], qh1 = qproj[bhi * ADIM + colb + 32];

    float sm0[16], sm1[16];
    #pragma unroll
    for (int i = 0; i < 16; i++) {
        const int pat = (i & 3) + 8 * (i >> 2) + 4 * h;
        {
            bool hi = (row0 + pat) >= split;
            sm0[i] = fast_tanh(c00[i] + (hi ? qh0 : ql0)) * v0
                   + fast_tanh(c01[i] + (hi ? qh1 : ql1)) * v1;
        }
        {
            bool hi = (row0 + 32 + pat) >= split;
            sm1[i] = fast_tanh(c10[i] + (hi ? qh0 : ql0)) * v0
                   + fast_tanh(c11[i] + (hi ? qh1 : ql1)) * v1;
        }
    }

    // reduce across the 32 col-lanes (h halves hold different rows)
    #pragma unroll
    for (int i = 0; i < 16; i++) {
        float t0 = sm0[i], t1 = sm1[i];
        t0 += __shfl_xor(t0, 1);  t1 += __shfl_xor(t1, 1);
        t0 += __shfl_xor(t0, 2);  t1 += __shfl_xor(t1, 2);
        t0 += __shfl_xor(t0, 4);  t1 += __shfl_xor(t1, 4);
        t0 += __shfl_xor(t0, 8);  t1 += __shfl_xor(t1, 8);
        t0 += __shfl_xor(t0, 16); t1 += __shfl_xor(t1, 16);
        sm0[i] = t0; sm1[i] = t1;
    }
    if (r == 0) {
        float* epw = ep + (size_t)wc * NROWS;
        #pragma unroll
        for (int i = 0; i < 16; i++) {
            const int pat = (i & 3) + 8 * (i >> 2) + 4 * h;
            epw[row0 + pat]      = sm0[i];
            epw[row0 + 32 + pat] = sm1[i];
        }
    }
}

// ---- K4: row softmax over summed partials -> aw -------------------------
__global__ void k_softmax(const float* __restrict__ ep, const int* __restrict__ mask,
                          float* __restrict__ aw) {
    int b = blockIdx.x;
    __shared__ float se[KLEN];
    __shared__ float redm[4], reds[4];
    int tid = threadIdx.x, lane = tid & 63, wv = tid >> 6;
    for (int k = tid; k < KLEN; k += 256) {
        int idx = b * KLEN + k;
        float val = 0.f;
        #pragma unroll
        for (int p = 0; p < 8; p++) val += ep[(size_t)p * NROWS + idx];
        se[k] = mask[idx] ? val : -3.4028235e38f;
    }
    __syncthreads();
    float m = -3.4028235e38f;
    for (int k = tid; k < KLEN; k += 256) m = fmaxf(m, se[k]);
    for (int o = 32; o; o >>= 1) m = fmaxf(m, __shfl_xor(m, o));
    if (lane == 0) redm[wv] = m;
    __syncthreads();
    m = fmaxf(fmaxf(redm[0], redm[1]), fmaxf(redm[2], redm[3]));
    float s = 0.f;
    for (int k = tid; k < KLEN; k += 256) s += __expf(se[k] - m);
    for (int o = 32; o; o >>= 1) s += __shfl_xor(s, o);
    if (lane == 0) reds[wv] = s;
    __syncthreads();
    s = reds[0] + reds[1] + reds[2] + reds[3];
    float inv = 1.0f / s;
    for (int k = tid; k < KLEN; k += 256) aw[b * KLEN + k] = __expf(se[k] - m) * inv;
}

// ---- K5a: partial cv over 16 k-chunks of 125 ----------------------------
__global__ void k_cvpart(const float* __restrict__ aw, const float* __restrict__ value,
                         float* __restrict__ part) {
    int b = blockIdx.x >> 4, chunk = blockIdx.x & 15;
    int k0 = chunk * 125;
    __shared__ float sa[125];
    int tid = threadIdx.x;
    if (tid < 125) sa[tid] = aw[b * KLEN + k0 + tid];
    __syncthreads();
    const float* vp = value + ((size_t)b * KLEN + k0) * VDIM + tid * 2;
    float ax = 0.f, ay = 0.f;
    #pragma unroll 5
    for (int k = 0; k < 125; k++) {
        const f32x2 vv = __builtin_nontemporal_load((const f32x2*)(vp + (size_t)k * VDIM));
        ax += sa[k] * vv[0]; ay += sa[k] * vv[1];
    }
    f32x2 o; o[0] = ax; o[1] = ay;
    *(f32x2*)(part + ((b * 16 + chunk) * VDIM) + tid * 2) = o;
}

// ---- K5b: reduce partials -> cv -----------------------------------------
__global__ void k_cvreduce(const float* __restrict__ part, float* __restrict__ cv) {
    int t = blockIdx.x * 256 + threadIdx.x;  // 16384
    int b = t >> 9, col = t & 511;
    float s = 0.f;
    #pragma unroll
    for (int c = 0; c < 16; c++) s += part[(b * 16 + c) * VDIM + col];
    cv[t] = s;
}

extern "C" void kernel_launch(void* const* d_in, const int* in_sizes, int n_in,
                              void* d_out, int out_size, void* d_ws, size_t ws_size,
                              hipStream_t stream) {
    const float* key     = (const float*)d_in[0];
    const float* value   = (const float*)d_in[1];
    const float* query   = (const float*)d_in[2];
    const float* aw_prev = (const float*)d_in[3];
    const int*   mask    = (const int*)d_in[4];
    const float* Wk      = (const float*)d_in[5];
    const float* bk      = (const float*)d_in[6];
    const float* Wq      = (const float*)d_in[7];
    const float* conv_w  = (const float*)d_in[8];
    const float* Wconv   = (const float*)d_in[9];
    const float* vvec    = (const float*)d_in[10];

    char* ws = (char*)d_ws;
    ushort* wp   = (ushort*)(ws + 0);          // 16*33*64*8*2 = 540672
    float* qproj = (float*)(ws + 540672);      // 32*512*4     = 65536
    float* cf    = (float*)(ws + 606208);      // 32*10*2000*4 = 2560000
    float* ep    = (float*)(ws + 3166208);     // 8*64000*4    = 2048000
    float* part  = (float*)(ws + 0);           // 32*16*512*4 = 1048576 (wp/qproj/cf dead by then)

    float* cv = (float*)d_out;                 // [32][512]
    float* aw = (float*)d_out + B * VDIM;      // [32][2000]

    k_pack_w  <<<132,  256, 0, stream>>>(Wk, Wconv, bk, wp);
    k_qproj   <<<64,   256, 0, stream>>>(query, Wq, qproj);
    k_conv    <<<2500, 256, 0, stream>>>(aw_prev, conv_w, cf);
    k_main    <<<1000, 512, 0, stream>>>(key, wp, qproj, cf, vvec, ep);
    k_softmax <<<B,    256, 0, stream>>>(ep, mask, aw);
    k_cvpart  <<<B*16, 256, 0, stream>>>(aw, value, part);
    k_cvreduce<<<64,   256, 0, stream>>>(part, cv);
}

// Round 9
// 157.454 us; speedup vs baseline: 1.0556x; 1.0556x over previous
//
#include <hip/hip_runtime.h>
#include <hip/hip_bf16.h>
#include <math.h>

#define B 32
#define KLEN 2000
#define KDIM 512
#define QDIM 512
#define ADIM 512
#define VDIM 512
#define CONV_CH 10
#define CONV_K 201
#define NROWS (B*KLEN)

#define NKS  33                  // 528 / 16 (512 key + 10 conv + 1 bias + 5 pad)
#define ZERO16 {0,0,0,0,0,0,0,0,0,0,0,0,0,0,0,0}

typedef __attribute__((ext_vector_type(8)))  short bf16x8;
typedef __attribute__((ext_vector_type(16))) float f32x16;
typedef __attribute__((ext_vector_type(4)))  float f32x4;
typedef __attribute__((ext_vector_type(2)))  float f32x2;

__device__ __forceinline__ ushort f32_to_bf16(float f) {
    union { float f; unsigned int u; } v; v.f = f;
    unsigned int x = v.u;
    unsigned int r = (x + 0x7FFFu + ((x >> 16) & 1u)) >> 16;
    return (ushort)r;
}

__device__ __forceinline__ float fast_tanh(float x) {
    // tanh(x) = 1 - 2/(e^(2x)+1); stable at both extremes
    return 1.0f - 2.0f / (__expf(2.0f * x) + 1.0f);
}

#define MFMA32(a, bfr, c) __builtin_amdgcn_mfma_f32_32x32x16_bf16(a, bfr, c, 0, 0, 0)

// ---- K0: pack W_ext = [Wk | Wconv | bk | 0pad] into MFMA-A lane layout ----
// layout: [nt(16)][ks(33)][lane(64)][8 bf16]; lane = h*32+r;
// holds W_ext[a = nt*32 + r][k = ks*16 + h*8 + jj]  (A-operand of swapped MFMA)
__global__ void k_pack_w(const float* __restrict__ Wk, const float* __restrict__ Wconv,
                         const float* __restrict__ bk, ushort* __restrict__ wp) {
    int t = blockIdx.x * 256 + threadIdx.x;        // 33792 16B-chunks
    int lane = t & 63;
    int idx = t >> 6;
    int ks = idx % NKS, nt = idx / NKS;
    int h = lane >> 5, r = lane & 31;
    int a = nt * 32 + r;
    int j0 = ks * 16 + h * 8;
    union { uint4 v; ushort u[8]; } pk;
    #pragma unroll
    for (int jj = 0; jj < 8; jj++) {
        int j = j0 + jj;
        float val;
        if (j < 512)       val = Wk[a * KDIM + j];
        else if (j < 522)  val = Wconv[a * CONV_CH + (j - 512)];
        else if (j == 522) val = bk[a];
        else               val = 0.f;
        pk.u[jj] = f32_to_bf16(val);
    }
    *(uint4*)(wp + (size_t)t * 8) = pk.v;
}

// ---- K1: qproj[b][a] = dot(query[b], Wq[a]) -----------------------------
__global__ void k_qproj(const float* __restrict__ query, const float* __restrict__ Wq,
                        float* __restrict__ qproj) {
    int t = blockIdx.x * 256 + threadIdx.x;        // 16384
    int b = t >> 9, a = t & 511;
    const f32x4* q = (const f32x4*)(query + b * QDIM);
    const f32x4* w = (const f32x4*)(Wq + a * QDIM);
    float acc = 0.f;
    #pragma unroll 4
    for (int i = 0; i < 128; i++) {
        f32x4 qv = q[i], wv = w[i];
        acc += qv[0]*wv[0] + qv[1]*wv[1] + qv[2]*wv[2] + qv[3]*wv[3];
    }
    qproj[t] = acc;
}

// ---- K2: conv_feat[b][c][k] = SAME cross-correlation --------------------
__global__ void k_conv(const float* __restrict__ aw_prev, const float* __restrict__ conv_w,
                       float* __restrict__ cf) {
    int t = blockIdx.x * 256 + threadIdx.x;
    if (t >= B * CONV_CH * KLEN) return;
    int k = t % KLEN;
    int c = (t / KLEN) % CONV_CH;
    int b = t / (KLEN * CONV_CH);
    const float* aw = aw_prev + b * KLEN;
    const float* w  = conv_w + c * CONV_K;
    int lo = k - 100;
    int t0 = lo < 0 ? -lo : 0;
    int t1 = (lo + CONV_K > KLEN) ? (KLEN - lo) : CONV_K;
    float acc = 0.f;
    for (int tt = t0; tt < t1; tt++) acc += w[tt] * aw[lo + tt];
    cf[t] = acc;
}

// ---- K3: fused kproj-ext GEMM + additive score (SWAPPED operands) -------
// D[row=a][col=key-row] = W_ext . key_ext  -> each lane owns ONE key-row,
// so the sum_a tanh(.)*v[a] is a per-lane serial sum (no cross-lane reduce).
// Block: 512 thr = 8 waves, each wave = 64 a-cols (2 a-tiles) x 64 key-rows.
// Blocks are batch-aligned: 32 blocks/batch x 64 rows (tail padded).
__global__ __launch_bounds__(512, 4)
void k_main(const float* __restrict__ key, const ushort* __restrict__ wp,
            const float* __restrict__ qproj, const float* __restrict__ cf,
            const float* __restrict__ vvec, const int* __restrict__ mask,
            float* __restrict__ e_out) {
    __shared__ char Alds[65536];                   // 64 key rows x 512 bf16, swizzled
    __shared__ float partsum[8][2][32];            // [wave][g][r] partial e
    const int tid = threadIdx.x;
    const int wc = tid >> 6, lane = tid & 63;      // wc = a-colgroup 0..7
    const int r = lane & 31, h = lane >> 5;
    const int b = blockIdx.x >> 5;                 // batch
    const int kbase = (blockIdx.x & 31) * 64;      // first key pos of block

    // ---- stage key rows (f32 -> bf16) into swizzled LDS -----------------
    #pragma unroll
    for (int i = 0; i < 8; i++) {
        int ch = tid + i * 512;
        int arow = ch >> 6, cx = ch & 63;
        int kpos = kbase + arow; if (kpos >= KLEN) kpos = KLEN - 1;  // clamp tail
        const float* kp = key + ((size_t)b * KLEN + kpos) * KDIM + cx * 8;
        f32x4 f0 = __builtin_nontemporal_load((const f32x4*)kp);
        f32x4 f1 = __builtin_nontemporal_load((const f32x4*)(kp + 4));
        union { uint4 v; ushort u[8]; } pk;
        pk.u[0] = f32_to_bf16(f0[0]); pk.u[1] = f32_to_bf16(f0[1]);
        pk.u[2] = f32_to_bf16(f0[2]); pk.u[3] = f32_to_bf16(f0[3]);
        pk.u[4] = f32_to_bf16(f1[0]); pk.u[5] = f32_to_bf16(f1[1]);
        pk.u[6] = f32_to_bf16(f1[2]); pk.u[7] = f32_to_bf16(f1[3]);
        int off = arow * 1024 + cx * 16;
        off ^= (arow & 31) << 4;
        *(uint4*)(Alds + off) = pk.v;
    }
    __syncthreads();

    // ---- main loop: W (A-op) from L2, key (B-op) from LDS ---------------
    const ushort* bpW0 = wp + ((size_t)(wc * 2 + 0) * NKS * 64 + lane) * 8;
    const ushort* bpW1 = wp + ((size_t)(wc * 2 + 1) * NKS * 64 + lane) * 8;
    const int base_g0 = r * 1024 + h * 16;
    const int base_g1 = base_g0 + 32768;
    const int swz = r << 4;

    f32x16 c00 = ZERO16, c01 = ZERO16;             // c[t][g]
    f32x16 c10 = ZERO16, c11 = ZERO16;

    #pragma unroll 4
    for (int ks = 0; ks < 32; ks++) {
        bf16x8 k0 = *(const bf16x8*)(Alds + ((base_g0 + ks * 32) ^ swz));
        bf16x8 k1 = *(const bf16x8*)(Alds + ((base_g1 + ks * 32) ^ swz));
        bf16x8 w0 = *(const bf16x8*)(bpW0 + ks * 512);
        bf16x8 w1 = *(const bf16x8*)(bpW1 + ks * 512);
        c00 = MFMA32(w0, k0, c00); c01 = MFMA32(w0, k1, c01);
        c10 = MFMA32(w1, k0, c10); c11 = MFMA32(w1, k1, c11);
    }
    {   // ks = 32: conv features + bias-one columns (B-op built in registers)
        auto build_ext = [&](int kpos) -> bf16x8 {
            int kc = kpos < KLEN ? kpos : KLEN - 1;
            const float* cfb = cf + ((size_t)b * CONV_CH) * KLEN + kc;
            union { bf16x8 v8; ushort u[8]; } pk;
            if (h == 0) {
                #pragma unroll
                for (int jj = 0; jj < 8; jj++) pk.u[jj] = f32_to_bf16(cfb[(size_t)jj * KLEN]);
            } else {
                pk.u[0] = f32_to_bf16(cfb[(size_t)8 * KLEN]);
                pk.u[1] = f32_to_bf16(cfb[(size_t)9 * KLEN]);
                pk.u[2] = 0x3F80;  // 1.0f bf16 (bias column)
                pk.u[3] = 0; pk.u[4] = 0; pk.u[5] = 0; pk.u[6] = 0; pk.u[7] = 0;
            }
            return pk.v8;
        };
        bf16x8 x0 = build_ext(kbase + r);
        bf16x8 x1 = build_ext(kbase + 32 + r);
        bf16x8 w0 = *(const bf16x8*)(bpW0 + 32 * 512);
        bf16x8 w1 = *(const bf16x8*)(bpW1 + 32 * 512);
        c00 = MFMA32(w0, x0, c00); c01 = MFMA32(w0, x1, c01);
        c10 = MFMA32(w1, x0, c10); c11 = MFMA32(w1, x1, c11);
    }

    // ---- epilogue: + qproj, tanh, * v — all per-lane --------------------
    // acc index i: a_local = (i&3) + 8*(i>>2) + 4*h  (contiguous 4s)
    const float* qb = qproj + b * ADIM + wc * 64;
    const float* vb = vvec + wc * 64;
    float pg0 = 0.f, pg1 = 0.f;
    #pragma unroll
    for (int t = 0; t < 2; t++) {
        const f32x16 a0 = t ? c10 : c00;
        const f32x16 a1 = t ? c11 : c01;
        #pragma unroll
        for (int q = 0; q < 4; q++) {
            f32x4 qv = *(const f32x4*)(qb + t * 32 + 8 * q + 4 * h);
            f32x4 vv = *(const f32x4*)(vb + t * 32 + 8 * q + 4 * h);
            #pragma unroll
            for (int j = 0; j < 4; j++) {
                int i = 4 * q + j;
                pg0 += fast_tanh(a0[i] + qv[j]) * vv[j];
                pg1 += fast_tanh(a1[i] + qv[j]) * vv[j];
            }
        }
    }
    // merge h-halves (each lane pair covers all 32 a's of both tiles)
    pg0 += __shfl_xor(pg0, 32);
    pg1 += __shfl_xor(pg1, 32);
    if (h == 0) { partsum[wc][0][r] = pg0; partsum[wc][1][r] = pg1; }
    __syncthreads();

    // ---- combine 8 waves' a-ranges, mask, write e -----------------------
    if (tid < 64) {
        int g = tid >> 5, rr = tid & 31;
        float s = 0.f;
        #pragma unroll
        for (int w = 0; w < 8; w++) s += partsum[w][g][rr];
        int kpos = kbase + g * 32 + rr;
        if (kpos < KLEN) {
            int idx = b * KLEN + kpos;
            e_out[idx] = mask[idx] ? s : -3.4028235e38f;
        }
    }
}

// ---- K4: row softmax -> aw ----------------------------------------------
__global__ void k_softmax(const float* __restrict__ e, float* __restrict__ aw) {
    int b = blockIdx.x;
    const float* er = e + b * KLEN;
    __shared__ float redm[4], reds[4];
    int tid = threadIdx.x, lane = tid & 63, wv = tid >> 6;
    float m = -3.4028235e38f;
    for (int k = tid; k < KLEN; k += 256) m = fmaxf(m, er[k]);
    for (int o = 32; o; o >>= 1) m = fmaxf(m, __shfl_xor(m, o));
    if (lane == 0) redm[wv] = m;
    __syncthreads();
    m = fmaxf(fmaxf(redm[0], redm[1]), fmaxf(redm[2], redm[3]));
    float s = 0.f;
    for (int k = tid; k < KLEN; k += 256) s += __expf(er[k] - m);
    for (int o = 32; o; o >>= 1) s += __shfl_xor(s, o);
    if (lane == 0) reds[wv] = s;
    __syncthreads();
    s = reds[0] + reds[1] + reds[2] + reds[3];
    float inv = 1.0f / s;
    for (int k = tid; k < KLEN; k += 256) aw[b * KLEN + k] = __expf(er[k] - m) * inv;
}

// ---- K5a: partial cv, f32x4/lane, 2 k-rows per iteration ----------------
__global__ void k_cvpart(const float* __restrict__ aw, const float* __restrict__ value,
                         float* __restrict__ part) {
    int b = blockIdx.x >> 3, chunk = blockIdx.x & 7;   // 8 chunks of 250 k
    int k0 = chunk * 250;
    __shared__ float sa[256];
    __shared__ f32x4 red[128];
    int tid = threadIdx.x;
    if (tid < 250) sa[tid] = aw[b * KLEN + k0 + tid];
    __syncthreads();
    const int kh = tid >> 7;            // which k of the pair
    const int col4 = (tid & 127) * 4;
    const float* vp = value + ((size_t)b * KLEN + k0 + kh) * VDIM + col4;
    f32x4 acc = {0.f, 0.f, 0.f, 0.f};
    #pragma unroll 5
    for (int k = 0; k < 250; k += 2) {
        f32x4 vv = __builtin_nontemporal_load((const f32x4*)(vp + (size_t)k * VDIM));
        acc += vv * sa[k + kh];
    }
    if (kh == 1) red[tid & 127] = acc;
    __syncthreads();
    if (kh == 0) {
        acc += red[tid];
        *(f32x4*)(part + ((b * 8 + chunk) * VDIM) + col4) = acc;
    }
}

// ---- K5b: reduce partials -> cv -----------------------------------------
__global__ void k_cvreduce(const float* __restrict__ part, float* __restrict__ cv) {
    int t = blockIdx.x * 256 + threadIdx.x;  // 16384
    int b = t >> 9, col = t & 511;
    float s = 0.f;
    #pragma unroll
    for (int c = 0; c < 8; c++) s += part[(b * 8 + c) * VDIM + col];
    cv[t] = s;
}

extern "C" void kernel_launch(void* const* d_in, const int* in_sizes, int n_in,
                              void* d_out, int out_size, void* d_ws, size_t ws_size,
                              hipStream_t stream) {
    const float* key     = (const float*)d_in[0];
    const float* value   = (const float*)d_in[1];
    const float* query   = (const float*)d_in[2];
    const float* aw_prev = (const float*)d_in[3];
    const int*   mask    = (const int*)d_in[4];
    const float* Wk      = (const float*)d_in[5];
    const float* bk      = (const float*)d_in[6];
    const float* Wq      = (const float*)d_in[7];
    const float* conv_w  = (const float*)d_in[8];
    const float* Wconv   = (const float*)d_in[9];
    const float* vvec    = (const float*)d_in[10];

    char* ws = (char*)d_ws;
    ushort* wp   = (ushort*)(ws + 0);          // 16*33*64*8*2 = 540672
    float* qproj = (float*)(ws + 540672);      // 32*512*4     = 65536
    float* cf    = (float*)(ws + 606208);      // 32*10*2000*4 = 2560000
    float* e     = (float*)(ws + 3166208);     // 32*2000*4    = 256000
    float* part  = (float*)(ws + 3422208);     // 32*8*512*4   = 524288

    float* cv = (float*)d_out;                 // [32][512]
    float* aw = (float*)d_out + B * VDIM;      // [32][2000]

    k_pack_w  <<<132,  256, 0, stream>>>(Wk, Wconv, bk, wp);
    k_qproj   <<<64,   256, 0, stream>>>(query, Wq, qproj);
    k_conv    <<<2500, 256, 0, stream>>>(aw_prev, conv_w, cf);
    k_main    <<<1024, 512, 0, stream>>>(key, wp, qproj, cf, vvec, mask, e);
    k_softmax <<<B,    256, 0, stream>>>(e, aw);
    k_cvpart  <<<B*8,  256, 0, stream>>>(aw, value, part);
    k_cvreduce<<<64,   256, 0, stream>>>(part, cv);
}

// Round 10
// 142.739 us; speedup vs baseline: 1.1644x; 1.1031x over previous
//
#include <hip/hip_runtime.h>
#include <hip/hip_bf16.h>
#include <math.h>

#define B 32
#define KLEN 2000
#define KDIM 512
#define QDIM 512
#define ADIM 512
#define VDIM 512
#define CONV_CH 10
#define CONV_K 201
#define NROWS (B*KLEN)

#define NKS  33                  // 528 / 16 (512 key + 10 conv + 1 bias + 5 pad)
#define ZERO16 {0,0,0,0,0,0,0,0,0,0,0,0,0,0,0,0}

// prep-kernel grid split
#define NP_PACK 53               // ceil(33792/640)
#define NP_QPRJ 26               // ceil(16384/640)
#define NP_CONV 256              // 32 b x 8 chunks of 256 k

typedef __attribute__((ext_vector_type(8)))  short bf16x8;
typedef __attribute__((ext_vector_type(16))) float f32x16;
typedef __attribute__((ext_vector_type(4)))  float f32x4;
typedef __attribute__((ext_vector_type(2)))  float f32x2;

__device__ __forceinline__ ushort f32_to_bf16(float f) {
    union { float f; unsigned int u; } v; v.f = f;
    unsigned int x = v.u;
    unsigned int r = (x + 0x7FFFu + ((x >> 16) & 1u)) >> 16;
    return (ushort)r;
}

__device__ __forceinline__ float fast_tanh(float x) {
    // tanh(x) = 1 - 2/(e^(2x)+1); stable at both extremes
    return 1.0f - 2.0f / (__expf(2.0f * x) + 1.0f);
}

#define MFMA32(a, bfr, c) __builtin_amdgcn_mfma_f32_32x32x16_bf16(a, bfr, c, 0, 0, 0)

// ---- K0: fused prep: pack W_ext | qproj | conv --------------------------
__global__ __launch_bounds__(640, 2)
void k_prep(const float* __restrict__ Wk, const float* __restrict__ Wconv,
            const float* __restrict__ bk, ushort* __restrict__ wp,
            const float* __restrict__ query, const float* __restrict__ Wq,
            float* __restrict__ qproj,
            const float* __restrict__ aw_prev, const float* __restrict__ conv_w,
            float* __restrict__ cf) {
    __shared__ float w_s[CONV_CH * 204];     // taps zero-padded to 204
    __shared__ float aw_s[464];              // k0-100 .. k0+363
    const int bid = blockIdx.x, tid = threadIdx.x;

    if (bid < NP_PACK) {
        // ---- pack W_ext = [Wk | Wconv | bk | 0pad] -> wp --------------
        // layout: [nt(16)][ks(33)][lane(64)][8 bf16]; lane = h*32+r;
        // holds W_ext[a = nt*32 + r][k = ks*16 + h*8 + jj]
        int t = bid * 640 + tid;
        if (t < 16 * NKS * 64) {
            int lane = t & 63;
            int idx = t >> 6;
            int ks = idx % NKS, nt = idx / NKS;
            int h = lane >> 5, r = lane & 31;
            int a = nt * 32 + r;
            int j0 = ks * 16 + h * 8;
            union { uint4 v; ushort u[8]; } pk;
            #pragma unroll
            for (int jj = 0; jj < 8; jj++) {
                int j = j0 + jj;
                float val;
                if (j < 512)       val = Wk[a * KDIM + j];
                else if (j < 522)  val = Wconv[a * CONV_CH + (j - 512)];
                else if (j == 522) val = bk[a];
                else               val = 0.f;
                pk.u[jj] = f32_to_bf16(val);
            }
            *(uint4*)(wp + (size_t)t * 8) = pk.v;
        }
    } else if (bid < NP_PACK + NP_QPRJ) {
        // ---- qproj[b][a] = dot(query[b], Wq[a]) -----------------------
        int t = (bid - NP_PACK) * 640 + tid;
        if (t < B * ADIM) {
            int b = t >> 9, a = t & 511;
            const f32x4* q = (const f32x4*)(query + b * QDIM);
            const f32x4* w = (const f32x4*)(Wq + a * QDIM);
            float acc = 0.f;
            #pragma unroll 4
            for (int i = 0; i < 128; i++) {
                f32x4 qv = q[i], wv = w[i];
                acc += qv[0]*wv[0] + qv[1]*wv[1] + qv[2]*wv[2] + qv[3]*wv[3];
            }
            qproj[t] = acc;
        }
    } else {
        // ---- conv: register-sliding-window cross-correlation ----------
        // block = (b, chunk of 256 k); wave = channel c; lane owns 4 k.
        int cb = bid - NP_PACK - NP_QPRJ;
        int b = cb >> 3, chunk = cb & 7;
        int k0 = chunk * 256;
        // stage taps (zero-padded to 204) and aw window
        for (int i = tid; i < CONV_CH * 204; i += 640) {
            int c = i / 204, t = i % 204;
            w_s[i] = (t < CONV_K) ? conv_w[c * CONV_K + t] : 0.f;
        }
        for (int i = tid; i < 464; i += 640) {
            int src = k0 - 100 + i;
            aw_s[i] = (src >= 0 && src < KLEN) ? aw_prev[b * KLEN + src] : 0.f;
        }
        __syncthreads();

        const int c = tid >> 6;                    // wave = channel
        const int k_local = (tid & 63) * 4;
        const float* wc = w_s + c * 204;
        float a0 = 0.f, a1 = 0.f, a2 = 0.f, a3 = 0.f;
        f32x4 r0 = *(const f32x4*)(aw_s + k_local);
        #pragma unroll 3
        for (int q = 0; q < 51; q++) {
            f32x4 r1 = *(const f32x4*)(aw_s + k_local + 4 * q + 4);
            float w0 = wc[4*q], w1 = wc[4*q+1], w2 = wc[4*q+2], w3 = wc[4*q+3];
            a0 += w0*r0[0]; a1 += w0*r0[1]; a2 += w0*r0[2]; a3 += w0*r0[3];
            a0 += w1*r0[1]; a1 += w1*r0[2]; a2 += w1*r0[3]; a3 += w1*r1[0];
            a0 += w2*r0[2]; a1 += w2*r0[3]; a2 += w2*r1[0]; a3 += w2*r1[1];
            a0 += w3*r0[3]; a1 += w3*r1[0]; a2 += w3*r1[1]; a3 += w3*r1[2];
            r0 = r1;
        }
        int k = k0 + k_local;
        float* dst = cf + ((size_t)b * CONV_CH + c) * KLEN + k;
        if (k + 3 < KLEN) {
            f32x4 o; o[0] = a0; o[1] = a1; o[2] = a2; o[3] = a3;
            *(f32x4*)dst = o;
        } else {
            if (k     < KLEN) dst[0] = a0;
            if (k + 1 < KLEN) dst[1] = a1;
            if (k + 2 < KLEN) dst[2] = a2;
            if (k + 3 < KLEN) dst[3] = a3;
        }
    }
}

// ---- K3: fused kproj-ext GEMM + additive score (SWAPPED operands) -------
// D[row=a][col=key-row] = W_ext . key_ext  -> each lane owns ONE key-row,
// so the sum_a tanh(.)*v[a] is a per-lane serial sum (no cross-lane reduce).
__global__ __launch_bounds__(512, 4)
void k_main(const float* __restrict__ key, const ushort* __restrict__ wp,
            const float* __restrict__ qproj, const float* __restrict__ cf,
            const float* __restrict__ vvec, const int* __restrict__ mask,
            float* __restrict__ e_out) {
    __shared__ char Alds[65536];                   // 64 key rows x 512 bf16, swizzled
    __shared__ float partsum[8][2][32];            // [wave][g][r] partial e
    const int tid = threadIdx.x;
    const int wc = tid >> 6, lane = tid & 63;      // wc = a-colgroup 0..7
    const int r = lane & 31, h = lane >> 5;
    const int b = blockIdx.x >> 5;                 // batch
    const int kbase = (blockIdx.x & 31) * 64;      // first key pos of block

    // ---- stage key rows (f32 -> bf16) into swizzled LDS -----------------
    #pragma unroll
    for (int i = 0; i < 8; i++) {
        int ch = tid + i * 512;
        int arow = ch >> 6, cx = ch & 63;
        int kpos = kbase + arow; if (kpos >= KLEN) kpos = KLEN - 1;  // clamp tail
        const float* kp = key + ((size_t)b * KLEN + kpos) * KDIM + cx * 8;
        f32x4 f0 = __builtin_nontemporal_load((const f32x4*)kp);
        f32x4 f1 = __builtin_nontemporal_load((const f32x4*)(kp + 4));
        union { uint4 v; ushort u[8]; } pk;
        pk.u[0] = f32_to_bf16(f0[0]); pk.u[1] = f32_to_bf16(f0[1]);
        pk.u[2] = f32_to_bf16(f0[2]); pk.u[3] = f32_to_bf16(f0[3]);
        pk.u[4] = f32_to_bf16(f1[0]); pk.u[5] = f32_to_bf16(f1[1]);
        pk.u[6] = f32_to_bf16(f1[2]); pk.u[7] = f32_to_bf16(f1[3]);
        int off = arow * 1024 + cx * 16;
        off ^= (arow & 31) << 4;
        *(uint4*)(Alds + off) = pk.v;
    }
    __syncthreads();

    // ---- main loop: W (A-op) from L2, key (B-op) from LDS ---------------
    const ushort* bpW0 = wp + ((size_t)(wc * 2 + 0) * NKS * 64 + lane) * 8;
    const ushort* bpW1 = wp + ((size_t)(wc * 2 + 1) * NKS * 64 + lane) * 8;
    const int base_g0 = r * 1024 + h * 16;
    const int base_g1 = base_g0 + 32768;
    const int swz = r << 4;

    f32x16 c00 = ZERO16, c01 = ZERO16;             // c[t][g]
    f32x16 c10 = ZERO16, c11 = ZERO16;

    #pragma unroll 4
    for (int ks = 0; ks < 32; ks++) {
        bf16x8 k0 = *(const bf16x8*)(Alds + ((base_g0 + ks * 32) ^ swz));
        bf16x8 k1 = *(const bf16x8*)(Alds + ((base_g1 + ks * 32) ^ swz));
        bf16x8 w0 = *(const bf16x8*)(bpW0 + ks * 512);
        bf16x8 w1 = *(const bf16x8*)(bpW1 + ks * 512);
        c00 = MFMA32(w0, k0, c00); c01 = MFMA32(w0, k1, c01);
        c10 = MFMA32(w1, k0, c10); c11 = MFMA32(w1, k1, c11);
    }
    {   // ks = 32: conv features + bias-one columns (B-op built in registers)
        auto build_ext = [&](int kpos) -> bf16x8 {
            int kc = kpos < KLEN ? kpos : KLEN - 1;
            const float* cfb = cf + ((size_t)b * CONV_CH) * KLEN + kc;
            union { bf16x8 v8; ushort u[8]; } pk;
            if (h == 0) {
                #pragma unroll
                for (int jj = 0; jj < 8; jj++) pk.u[jj] = f32_to_bf16(cfb[(size_t)jj * KLEN]);
            } else {
                pk.u[0] = f32_to_bf16(cfb[(size_t)8 * KLEN]);
                pk.u[1] = f32_to_bf16(cfb[(size_t)9 * KLEN]);
                pk.u[2] = 0x3F80;  // 1.0f bf16 (bias column)
                pk.u[3] = 0; pk.u[4] = 0; pk.u[5] = 0; pk.u[6] = 0; pk.u[7] = 0;
            }
            return pk.v8;
        };
        bf16x8 x0 = build_ext(kbase + r);
        bf16x8 x1 = build_ext(kbase + 32 + r);
        bf16x8 w0 = *(const bf16x8*)(bpW0 + 32 * 512);
        bf16x8 w1 = *(const bf16x8*)(bpW1 + 32 * 512);
        c00 = MFMA32(w0, x0, c00); c01 = MFMA32(w0, x1, c01);
        c10 = MFMA32(w1, x0, c10); c11 = MFMA32(w1, x1, c11);
    }

    // ---- epilogue: + qproj, tanh, * v — all per-lane --------------------
    const float* qb = qproj + b * ADIM + wc * 64;
    const float* vb = vvec + wc * 64;
    float pg0 = 0.f, pg1 = 0.f;
    #pragma unroll
    for (int t = 0; t < 2; t++) {
        const f32x16 a0 = t ? c10 : c00;
        const f32x16 a1 = t ? c11 : c01;
        #pragma unroll
        for (int q = 0; q < 4; q++) {
            f32x4 qv = *(const f32x4*)(qb + t * 32 + 8 * q + 4 * h);
            f32x4 vv = *(const f32x4*)(vb + t * 32 + 8 * q + 4 * h);
            #pragma unroll
            for (int j = 0; j < 4; j++) {
                int i = 4 * q + j;
                pg0 += fast_tanh(a0[i] + qv[j]) * vv[j];
                pg1 += fast_tanh(a1[i] + qv[j]) * vv[j];
            }
        }
    }
    // merge h-halves (each lane pair covers all 32 a's of both tiles)
    pg0 += __shfl_xor(pg0, 32);
    pg1 += __shfl_xor(pg1, 32);
    if (h == 0) { partsum[wc][0][r] = pg0; partsum[wc][1][r] = pg1; }
    __syncthreads();

    // ---- combine 8 waves' a-ranges, mask, write e -----------------------
    if (tid < 64) {
        int g = tid >> 5, rr = tid & 31;
        float s = 0.f;
        #pragma unroll
        for (int w = 0; w < 8; w++) s += partsum[w][g][rr];
        int kpos = kbase + g * 32 + rr;
        if (kpos < KLEN) {
            int idx = b * KLEN + kpos;
            e_out[idx] = mask[idx] ? s : -3.4028235e38f;
        }
    }
}

// ---- K4: row softmax -> aw ----------------------------------------------
__global__ void k_softmax(const float* __restrict__ e, float* __restrict__ aw) {
    int b = blockIdx.x;
    const float* er = e + b * KLEN;
    __shared__ float redm[4], reds[4];
    int tid = threadIdx.x, lane = tid & 63, wv = tid >> 6;
    float m = -3.4028235e38f;
    for (int k = tid; k < KLEN; k += 256) m = fmaxf(m, er[k]);
    for (int o = 32; o; o >>= 1) m = fmaxf(m, __shfl_xor(m, o));
    if (lane == 0) redm[wv] = m;
    __syncthreads();
    m = fmaxf(fmaxf(redm[0], redm[1]), fmaxf(redm[2], redm[3]));
    float s = 0.f;
    for (int k = tid; k < KLEN; k += 256) s += __expf(er[k] - m);
    for (int o = 32; o; o >>= 1) s += __shfl_xor(s, o);
    if (lane == 0) reds[wv] = s;
    __syncthreads();
    s = reds[0] + reds[1] + reds[2] + reds[3];
    float inv = 1.0f / s;
    for (int k = tid; k < KLEN; k += 256) aw[b * KLEN + k] = __expf(er[k] - m) * inv;
}

// ---- K5a: partial cv, 16 chunks x 512 thr (4-way k split) ---------------
__global__ __launch_bounds__(512, 2)
void k_cvpart(const float* __restrict__ aw, const float* __restrict__ value,
              float* __restrict__ part) {
    int b = blockIdx.x >> 4, chunk = blockIdx.x & 15;   // 16 chunks of 125 k
    int k0 = chunk * 125;
    __shared__ float sa[128];
    __shared__ f32x4 red[3][128];
    int tid = threadIdx.x;
    if (tid < 125) sa[tid] = aw[b * KLEN + k0 + tid];
    __syncthreads();
    const int kh = tid >> 7;            // 0..3
    const int colt = tid & 127;
    const float* vp = value + ((size_t)b * KLEN + k0) * VDIM + colt * 4;
    f32x4 acc = {0.f, 0.f, 0.f, 0.f};
    for (int k = kh; k < 125; k += 4) {
        f32x4 vv = __builtin_nontemporal_load((const f32x4*)(vp + (size_t)k * VDIM));
        acc += vv * sa[k];
    }
    if (kh) red[kh - 1][colt] = acc;
    __syncthreads();
    if (kh == 0) {
        acc += red[0][colt] + red[1][colt] + red[2][colt];
        *(f32x4*)(part + ((b * 16 + chunk) * VDIM) + colt * 4) = acc;
    }
}

// ---- K5b: reduce partials -> cv -----------------------------------------
__global__ void k_cvreduce(const float* __restrict__ part, float* __restrict__ cv) {
    int t = blockIdx.x * 256 + threadIdx.x;  // 16384
    int b = t >> 9, col = t & 511;
    float s = 0.f;
    #pragma unroll
    for (int c = 0; c < 16; c++) s += part[(b * 16 + c) * VDIM + col];
    cv[t] = s;
}

extern "C" void kernel_launch(void* const* d_in, const int* in_sizes, int n_in,
                              void* d_out, int out_size, void* d_ws, size_t ws_size,
                              hipStream_t stream) {
    const float* key     = (const float*)d_in[0];
    const float* value   = (const float*)d_in[1];
    const float* query   = (const float*)d_in[2];
    const float* aw_prev = (const float*)d_in[3];
    const int*   mask    = (const int*)d_in[4];
    const float* Wk      = (const float*)d_in[5];
    const float* bk      = (const float*)d_in[6];
    const float* Wq      = (const float*)d_in[7];
    const float* conv_w  = (const float*)d_in[8];
    const float* Wconv   = (const float*)d_in[9];
    const float* vvec    = (const float*)d_in[10];

    char* ws = (char*)d_ws;
    ushort* wp   = (ushort*)(ws + 0);          // 16*33*64*8*2 = 540672
    float* qproj = (float*)(ws + 540672);      // 32*512*4     = 65536
    float* cf    = (float*)(ws + 606208);      // 32*10*2000*4 = 2560000
    float* e     = (float*)(ws + 3166208);     // 32*2000*4    = 256000
    float* part  = (float*)(ws + 3422208);     // 32*16*512*4  = 1048576

    float* cv = (float*)d_out;                 // [32][512]
    float* aw = (float*)d_out + B * VDIM;      // [32][2000]

    k_prep    <<<NP_PACK + NP_QPRJ + NP_CONV, 640, 0, stream>>>(
                  Wk, Wconv, bk, wp, query, Wq, qproj, aw_prev, conv_w, cf);
    k_main    <<<1024, 512, 0, stream>>>(key, wp, qproj, cf, vvec, mask, e);
    k_softmax <<<B,    256, 0, stream>>>(e, aw);
    k_cvpart  <<<B*16, 512, 0, stream>>>(aw, value, part);
    k_cvreduce<<<64,   256, 0, stream>>>(part, cv);
}

// Round 11
// 141.834 us; speedup vs baseline: 1.1718x; 1.0064x over previous
//
#include <hip/hip_runtime.h>
#include <hip/hip_bf16.h>
#include <math.h>

#define B 32
#define KLEN 2000
#define KDIM 512
#define QDIM 512
#define ADIM 512
#define VDIM 512
#define CONV_CH 10
#define CONV_K 201
#define NROWS (B*KLEN)

#define NKS  33                  // 528 / 16 (512 key + 10 conv + 1 bias + 5 pad)
#define ZERO16 {0,0,0,0,0,0,0,0,0,0,0,0,0,0,0,0}

// prep-kernel grid split
#define NP_PACK 53               // ceil(33792/640)
#define NP_QPRJ 26               // ceil(16384/640)
#define NP_ZERO 26               // ceil(16384/640) zero cv
#define NP_CONV 256              // 32 b x 8 chunks of 256 k

// cvpart chunking
#define CH_LEN 63                // 32 chunks x 63 >= 2000
#define CH_N   32

typedef __attribute__((ext_vector_type(8)))  short bf16x8;
typedef __attribute__((ext_vector_type(16))) float f32x16;
typedef __attribute__((ext_vector_type(4)))  float f32x4;
typedef __attribute__((ext_vector_type(2)))  float f32x2;

__device__ __forceinline__ ushort f32_to_bf16(float f) {
    union { float f; unsigned int u; } v; v.f = f;
    unsigned int x = v.u;
    unsigned int r = (x + 0x7FFFu + ((x >> 16) & 1u)) >> 16;
    return (ushort)r;
}

__device__ __forceinline__ float fast_tanh(float x) {
    // tanh(x) = 1 - 2/(e^(2x)+1); stable at both extremes
    return 1.0f - 2.0f / (__expf(2.0f * x) + 1.0f);
}

#define MFMA32(a, bfr, c) __builtin_amdgcn_mfma_f32_32x32x16_bf16(a, bfr, c, 0, 0, 0)

// ---- K0: fused prep: pack W_ext | qproj | zero cv | conv ----------------
__global__ __launch_bounds__(640, 2)
void k_prep(const float* __restrict__ Wk, const float* __restrict__ Wconv,
            const float* __restrict__ bk, ushort* __restrict__ wp,
            const float* __restrict__ query, const float* __restrict__ Wq,
            float* __restrict__ qproj,
            const float* __restrict__ aw_prev, const float* __restrict__ conv_w,
            float* __restrict__ cf, float* __restrict__ cv) {
    __shared__ float w_s[CONV_CH * 204];     // taps zero-padded to 204
    __shared__ float aw_s[464];              // k0-100 .. k0+363
    const int bid = blockIdx.x, tid = threadIdx.x;

    if (bid < NP_PACK) {
        // ---- pack W_ext = [Wk | Wconv | bk | 0pad] -> wp --------------
        int t = bid * 640 + tid;
        if (t < 16 * NKS * 64) {
            int lane = t & 63;
            int idx = t >> 6;
            int ks = idx % NKS, nt = idx / NKS;
            int h = lane >> 5, r = lane & 31;
            int a = nt * 32 + r;
            int j0 = ks * 16 + h * 8;
            union { uint4 v; ushort u[8]; } pk;
            #pragma unroll
            for (int jj = 0; jj < 8; jj++) {
                int j = j0 + jj;
                float val;
                if (j < 512)       val = Wk[a * KDIM + j];
                else if (j < 522)  val = Wconv[a * CONV_CH + (j - 512)];
                else if (j == 522) val = bk[a];
                else               val = 0.f;
                pk.u[jj] = f32_to_bf16(val);
            }
            *(uint4*)(wp + (size_t)t * 8) = pk.v;
        }
    } else if (bid < NP_PACK + NP_QPRJ) {
        // ---- qproj[b][a] = dot(query[b], Wq[a]) -----------------------
        int t = (bid - NP_PACK) * 640 + tid;
        if (t < B * ADIM) {
            int b = t >> 9, a = t & 511;
            const f32x4* q = (const f32x4*)(query + b * QDIM);
            const f32x4* w = (const f32x4*)(Wq + a * QDIM);
            float acc = 0.f;
            #pragma unroll 4
            for (int i = 0; i < 128; i++) {
                f32x4 qv = q[i], wv = w[i];
                acc += qv[0]*wv[0] + qv[1]*wv[1] + qv[2]*wv[2] + qv[3]*wv[3];
            }
            qproj[t] = acc;
        }
    } else if (bid < NP_PACK + NP_QPRJ + NP_ZERO) {
        // ---- zero cv (atomic target) ----------------------------------
        int t = (bid - NP_PACK - NP_QPRJ) * 640 + tid;
        if (t < B * VDIM) cv[t] = 0.f;
    } else {
        // ---- conv: register-sliding-window cross-correlation ----------
        int cb = bid - NP_PACK - NP_QPRJ - NP_ZERO;
        int b = cb >> 3, chunk = cb & 7;
        int k0 = chunk * 256;
        for (int i = tid; i < CONV_CH * 204; i += 640) {
            int c = i / 204, t = i % 204;
            w_s[i] = (t < CONV_K) ? conv_w[c * CONV_K + t] : 0.f;
        }
        for (int i = tid; i < 464; i += 640) {
            int src = k0 - 100 + i;
            aw_s[i] = (src >= 0 && src < KLEN) ? aw_prev[b * KLEN + src] : 0.f;
        }
        __syncthreads();

        const int c = tid >> 6;                    // wave = channel
        const int k_local = (tid & 63) * 4;
        const float* wc = w_s + c * 204;
        float a0 = 0.f, a1 = 0.f, a2 = 0.f, a3 = 0.f;
        f32x4 r0 = *(const f32x4*)(aw_s + k_local);
        #pragma unroll 3
        for (int q = 0; q < 51; q++) {
            f32x4 r1 = *(const f32x4*)(aw_s + k_local + 4 * q + 4);
            float w0 = wc[4*q], w1 = wc[4*q+1], w2 = wc[4*q+2], w3 = wc[4*q+3];
            a0 += w0*r0[0]; a1 += w0*r0[1]; a2 += w0*r0[2]; a3 += w0*r0[3];
            a0 += w1*r0[1]; a1 += w1*r0[2]; a2 += w1*r0[3]; a3 += w1*r1[0];
            a0 += w2*r0[2]; a1 += w2*r0[3]; a2 += w2*r1[0]; a3 += w2*r1[1];
            a0 += w3*r0[3]; a1 += w3*r1[0]; a2 += w3*r1[1]; a3 += w3*r1[2];
            r0 = r1;
        }
        int k = k0 + k_local;
        float* dst = cf + ((size_t)b * CONV_CH + c) * KLEN + k;
        if (k + 3 < KLEN) {
            f32x4 o; o[0] = a0; o[1] = a1; o[2] = a2; o[3] = a3;
            *(f32x4*)dst = o;
        } else {
            if (k     < KLEN) dst[0] = a0;
            if (k + 1 < KLEN) dst[1] = a1;
            if (k + 2 < KLEN) dst[2] = a2;
            if (k + 3 < KLEN) dst[3] = a3;
        }
    }
}

// ---- K3: fused kproj-ext GEMM + additive score (SWAPPED operands) -------
__global__ __launch_bounds__(512, 4)
void k_main(const float* __restrict__ key, const ushort* __restrict__ wp,
            const float* __restrict__ qproj, const float* __restrict__ cf,
            const float* __restrict__ vvec, const int* __restrict__ mask,
            float* __restrict__ e_out) {
    __shared__ char Alds[65536];                   // 64 key rows x 512 bf16, swizzled
    __shared__ float partsum[8][2][32];            // [wave][g][r] partial e
    const int tid = threadIdx.x;
    const int wc = tid >> 6, lane = tid & 63;      // wc = a-colgroup 0..7
    const int r = lane & 31, h = lane >> 5;
    const int b = blockIdx.x >> 5;                 // batch
    const int kbase = (blockIdx.x & 31) * 64;      // first key pos of block

    // ---- stage key rows (f32 -> bf16) into swizzled LDS -----------------
    #pragma unroll
    for (int i = 0; i < 8; i++) {
        int ch = tid + i * 512;
        int arow = ch >> 6, cx = ch & 63;
        int kpos = kbase + arow; if (kpos >= KLEN) kpos = KLEN - 1;  // clamp tail
        const float* kp = key + ((size_t)b * KLEN + kpos) * KDIM + cx * 8;
        f32x4 f0 = __builtin_nontemporal_load((const f32x4*)kp);
        f32x4 f1 = __builtin_nontemporal_load((const f32x4*)(kp + 4));
        union { uint4 v; ushort u[8]; } pk;
        pk.u[0] = f32_to_bf16(f0[0]); pk.u[1] = f32_to_bf16(f0[1]);
        pk.u[2] = f32_to_bf16(f0[2]); pk.u[3] = f32_to_bf16(f0[3]);
        pk.u[4] = f32_to_bf16(f1[0]); pk.u[5] = f32_to_bf16(f1[1]);
        pk.u[6] = f32_to_bf16(f1[2]); pk.u[7] = f32_to_bf16(f1[3]);
        int off = arow * 1024 + cx * 16;
        off ^= (arow & 31) << 4;
        *(uint4*)(Alds + off) = pk.v;
    }
    __syncthreads();

    // ---- main loop: W (A-op) from L2, key (B-op) from LDS ---------------
    const ushort* bpW0 = wp + ((size_t)(wc * 2 + 0) * NKS * 64 + lane) * 8;
    const ushort* bpW1 = wp + ((size_t)(wc * 2 + 1) * NKS * 64 + lane) * 8;
    const int base_g0 = r * 1024 + h * 16;
    const int base_g1 = base_g0 + 32768;
    const int swz = r << 4;

    f32x16 c00 = ZERO16, c01 = ZERO16;             // c[t][g]
    f32x16 c10 = ZERO16, c11 = ZERO16;

    #pragma unroll 4
    for (int ks = 0; ks < 32; ks++) {
        bf16x8 k0 = *(const bf16x8*)(Alds + ((base_g0 + ks * 32) ^ swz));
        bf16x8 k1 = *(const bf16x8*)(Alds + ((base_g1 + ks * 32) ^ swz));
        bf16x8 w0 = *(const bf16x8*)(bpW0 + ks * 512);
        bf16x8 w1 = *(const bf16x8*)(bpW1 + ks * 512);
        c00 = MFMA32(w0, k0, c00); c01 = MFMA32(w0, k1, c01);
        c10 = MFMA32(w1, k0, c10); c11 = MFMA32(w1, k1, c11);
    }
    {   // ks = 32: conv features + bias-one columns (B-op built in registers)
        auto build_ext = [&](int kpos) -> bf16x8 {
            int kc = kpos < KLEN ? kpos : KLEN - 1;
            const float* cfb = cf + ((size_t)b * CONV_CH) * KLEN + kc;
            union { bf16x8 v8; ushort u[8]; } pk;
            if (h == 0) {
                #pragma unroll
                for (int jj = 0; jj < 8; jj++) pk.u[jj] = f32_to_bf16(cfb[(size_t)jj * KLEN]);
            } else {
                pk.u[0] = f32_to_bf16(cfb[(size_t)8 * KLEN]);
                pk.u[1] = f32_to_bf16(cfb[(size_t)9 * KLEN]);
                pk.u[2] = 0x3F80;  // 1.0f bf16 (bias column)
                pk.u[3] = 0; pk.u[4] = 0; pk.u[5] = 0; pk.u[6] = 0; pk.u[7] = 0;
            }
            return pk.v8;
        };
        bf16x8 x0 = build_ext(kbase + r);
        bf16x8 x1 = build_ext(kbase + 32 + r);
        bf16x8 w0 = *(const bf16x8*)(bpW0 + 32 * 512);
        bf16x8 w1 = *(const bf16x8*)(bpW1 + 32 * 512);
        c00 = MFMA32(w0, x0, c00); c01 = MFMA32(w0, x1, c01);
        c10 = MFMA32(w1, x0, c10); c11 = MFMA32(w1, x1, c11);
    }

    // ---- epilogue: + qproj, tanh, * v — all per-lane --------------------
    const float* qb = qproj + b * ADIM + wc * 64;
    const float* vb = vvec + wc * 64;
    float pg0 = 0.f, pg1 = 0.f;
    #pragma unroll
    for (int t = 0; t < 2; t++) {
        const f32x16 a0 = t ? c10 : c00;
        const f32x16 a1 = t ? c11 : c01;
        #pragma unroll
        for (int q = 0; q < 4; q++) {
            f32x4 qv = *(const f32x4*)(qb + t * 32 + 8 * q + 4 * h);
            f32x4 vv = *(const f32x4*)(vb + t * 32 + 8 * q + 4 * h);
            #pragma unroll
            for (int j = 0; j < 4; j++) {
                int i = 4 * q + j;
                pg0 += fast_tanh(a0[i] + qv[j]) * vv[j];
                pg1 += fast_tanh(a1[i] + qv[j]) * vv[j];
            }
        }
    }
    pg0 += __shfl_xor(pg0, 32);
    pg1 += __shfl_xor(pg1, 32);
    if (h == 0) { partsum[wc][0][r] = pg0; partsum[wc][1][r] = pg1; }
    __syncthreads();

    if (tid < 64) {
        int g = tid >> 5, rr = tid & 31;
        float s = 0.f;
        #pragma unroll
        for (int w = 0; w < 8; w++) s += partsum[w][g][rr];
        int kpos = kbase + g * 32 + rr;
        if (kpos < KLEN) {
            int idx = b * KLEN + kpos;
            e_out[idx] = mask[idx] ? s : -3.4028235e38f;
        }
    }
}

// ---- K4: per-batch softmax stats {m, 1/s} -------------------------------
__global__ void k_stats(const float* __restrict__ e, float* __restrict__ stats) {
    int b = blockIdx.x;
    const float* er = e + b * KLEN;
    __shared__ float redm[4], reds[4];
    int tid = threadIdx.x, lane = tid & 63, wv = tid >> 6;
    float m = -3.4028235e38f;
    for (int k = tid; k < KLEN; k += 256) m = fmaxf(m, er[k]);
    for (int o = 32; o; o >>= 1) m = fmaxf(m, __shfl_xor(m, o));
    if (lane == 0) redm[wv] = m;
    __syncthreads();
    m = fmaxf(fmaxf(redm[0], redm[1]), fmaxf(redm[2], redm[3]));
    float s = 0.f;
    for (int k = tid; k < KLEN; k += 256) s += __expf(er[k] - m);
    for (int o = 32; o; o >>= 1) s += __shfl_xor(s, o);
    if (lane == 0) reds[wv] = s;
    __syncthreads();
    if (tid == 0) {
        s = reds[0] + reds[1] + reds[2] + reds[3];
        stats[b * 2] = m;
        stats[b * 2 + 1] = 1.0f / s;
    }
}

// ---- K5: cv partial with inline softmax apply + aw write + atomic cv ----
__global__ __launch_bounds__(512, 4)
void k_cvpart(const float* __restrict__ e, const float* __restrict__ stats,
              const float* __restrict__ value, float* __restrict__ aw,
              float* __restrict__ cv) {
    int b = blockIdx.x >> 5, chunk = blockIdx.x & 31;   // 32 chunks of 63 k
    int k0 = chunk * CH_LEN;
    int len = KLEN - k0; if (len > CH_LEN) len = CH_LEN;
    __shared__ float sa[CH_LEN + 1];
    __shared__ f32x4 red[3][128];
    int tid = threadIdx.x;
    if (tid < len) {
        float m = stats[b * 2], inv = stats[b * 2 + 1];
        float p = __expf(e[b * KLEN + k0 + tid] - m) * inv;
        sa[tid] = p;
        aw[b * KLEN + k0 + tid] = p;
    }
    __syncthreads();
    const int kh = tid >> 7;            // 0..3
    const int colt = tid & 127;
    const float* vp = value + ((size_t)b * KLEN + k0) * VDIM + colt * 4;
    f32x4 acc = {0.f, 0.f, 0.f, 0.f};
    for (int k = kh; k < len; k += 4) {
        f32x4 vv = *(const f32x4*)(vp + (size_t)k * VDIM);
        acc += vv * sa[k];
    }
    if (kh) red[kh - 1][colt] = acc;
    __syncthreads();
    if (kh == 0) {
        acc += red[0][colt] + red[1][colt] + red[2][colt];
        float* dst = cv + b * VDIM + colt * 4;
        atomicAdd(dst + 0, acc[0]);
        atomicAdd(dst + 1, acc[1]);
        atomicAdd(dst + 2, acc[2]);
        atomicAdd(dst + 3, acc[3]);
    }
}

extern "C" void kernel_launch(void* const* d_in, const int* in_sizes, int n_in,
                              void* d_out, int out_size, void* d_ws, size_t ws_size,
                              hipStream_t stream) {
    const float* key     = (const float*)d_in[0];
    const float* value   = (const float*)d_in[1];
    const float* query   = (const float*)d_in[2];
    const float* aw_prev = (const float*)d_in[3];
    const int*   mask    = (const int*)d_in[4];
    const float* Wk      = (const float*)d_in[5];
    const float* bk      = (const float*)d_in[6];
    const float* Wq      = (const float*)d_in[7];
    const float* conv_w  = (const float*)d_in[8];
    const float* Wconv   = (const float*)d_in[9];
    const float* vvec    = (const float*)d_in[10];

    char* ws = (char*)d_ws;
    ushort* wp   = (ushort*)(ws + 0);          // 16*33*64*8*2 = 540672
    float* qproj = (float*)(ws + 540672);      // 32*512*4     = 65536
    float* cf    = (float*)(ws + 606208);      // 32*10*2000*4 = 2560000
    float* e     = (float*)(ws + 3166208);     // 32*2000*4    = 256000
    float* stats = (float*)(ws + 3422208);     // 32*2*4       = 256

    float* cv = (float*)d_out;                 // [32][512]
    float* aw = (float*)d_out + B * VDIM;      // [32][2000]

    k_prep  <<<NP_PACK + NP_QPRJ + NP_ZERO + NP_CONV, 640, 0, stream>>>(
                Wk, Wconv, bk, wp, query, Wq, qproj, aw_prev, conv_w, cf, cv);
    k_main  <<<1024, 512, 0, stream>>>(key, wp, qproj, cf, vvec, mask, e);
    k_stats <<<B,    256, 0, stream>>>(e, stats);
    k_cvpart<<<B*32, 512, 0, stream>>>(e, stats, value, aw, cv);
}